// Round 1
// baseline (107.867 us; speedup 1.0000x reference)
//
#include <hip/hip_runtime.h>
#include <math.h>

// GP_conv2D: N=8, IH=IW=32, IC=8, OC=16, 3x3 s1 p1, P=5, I_DIM=72
#define OC_N   16
#define I_DIM  72
#define PN     5
#define NEU    (OC_N * I_DIM)   // 1152
#define NF     32               // floats per neuron record (128 B)
#define RTOT   8192             // N * OH * OW
#define OUT_HALF (RTOT * OC_N)  // 131072

#if __has_builtin(__builtin_amdgcn_rcpf)
#define RCPF(x) __builtin_amdgcn_rcpf(x)
#else
#define RCPF(x) (1.0f / (x))
#endif
#if __has_builtin(__builtin_amdgcn_exp2f)
#define EXP2F(x) __builtin_amdgcn_exp2f(x)
#else
#define EXP2F(x) exp2f(x)
#endif

// Neuron record layout (32 floats):
// [0]=l2  [1]=pad  [2..6]=z[p]  [7..11]=alpha[p]
// [12..16]=Kinv diag  [17..26]=2*Kinv offdiag (01,02,03,04,12,13,14,23,24,34)
// [27..31]=pad

__global__ void gp_prep_kernel(const float* __restrict__ zin,
                               const float* __restrict__ hin,
                               const float* __restrict__ rlin,
                               float* __restrict__ nr) {
  int idx = blockIdx.x * blockDim.x + threadIdx.x;
  if (idx >= NEU) return;
  double x = (double)rlin[idx];
  double sp = (x > 30.0) ? x : log1p(exp(x));   // softplus
  double l2 = sp * sp;
  double zz[PN], hh[PN];
#pragma unroll
  for (int p = 0; p < PN; ++p) {
    zz[p] = (double)zin[idx * PN + p];
    hh[p] = (double)hin[idx * PN + p];
  }
  double A[PN][PN], B[PN][PN];
#pragma unroll
  for (int p = 0; p < PN; ++p) {
#pragma unroll
    for (int q = 0; q < PN; ++q) {
      double dz = zz[p] - zz[q];
      A[p][q] = exp(-0.5 * dz * dz / l2);
      B[p][q] = (p == q) ? 1.0 : 0.0;
    }
  }
#pragma unroll
  for (int p = 0; p < PN; ++p) A[p][p] += 1e-4;  // jitter (exp(0)=1 already in)

  // Gauss-Jordan inverse (SPD + jitter -> no pivoting needed), fp64
  for (int c = 0; c < PN; ++c) {
    double pivinv = 1.0 / A[c][c];
    for (int j = 0; j < PN; ++j) { A[c][j] *= pivinv; B[c][j] *= pivinv; }
    for (int r = 0; r < PN; ++r) {
      if (r == c) continue;
      double f = A[r][c];
      for (int j = 0; j < PN; ++j) { A[r][j] -= f * A[c][j]; B[r][j] -= f * B[c][j]; }
    }
  }
  double alpha[PN];
#pragma unroll
  for (int p = 0; p < PN; ++p) {
    double s = 0.0;
    for (int q = 0; q < PN; ++q) s += B[p][q] * hh[q];
    alpha[p] = s;
  }
  float* o = nr + idx * NF;
  o[0] = (float)l2;
  o[1] = 0.0f;
#pragma unroll
  for (int p = 0; p < PN; ++p) {
    o[2 + p]  = (float)zz[p];
    o[7 + p]  = (float)alpha[p];
    o[12 + p] = (float)B[p][p];
  }
  int j = 17;
  for (int p = 0; p < PN; ++p)
    for (int q = p + 1; q < PN; ++q) o[j++] = (float)(2.0 * B[p][q]);
  o[27] = o[28] = o[29] = o[30] = o[31] = 0.0f;
}

__global__ __launch_bounds__(256) void gp_main_kernel(
    const float* __restrict__ xm, const float* __restrict__ xv,
    const float* __restrict__ nr, float* __restrict__ out) {
  const int o = blockIdx.y;                       // wave-uniform channel
  const int r = blockIdx.x * 256 + threadIdx.x;   // im2col row, 0..8191
  const int n  = r >> 10;
  const int pix = r & 1023;
  const int oh = pix >> 5;
  const int ow = pix & 31;
  const float* nb = nr + o * (I_DIM * NF);

  float mean_acc = 0.0f;
  float qkq_acc  = 0.0f;

#pragma unroll 1
  for (int k = 0; k < 9; ++k) {            // kernel tap = kh*3+kw
    const int kh = k / 3;
    const int kw = k - kh * 3;
    const int ih = oh + kh - 1;
    const int iw = ow + kw - 1;
    const bool vld = ((unsigned)ih < 32u) & ((unsigned)iw < 32u);
    float mu[8], s2[8];
    if (vld) {
      const int base = ((n * 32 + ih) * 32 + iw) * 8;   // 32B-aligned
      const float4 a0 = *(const float4*)(xm + base);
      const float4 a1 = *(const float4*)(xm + base + 4);
      const float4 b0 = *(const float4*)(xv + base);
      const float4 b1 = *(const float4*)(xv + base + 4);
      mu[0]=a0.x; mu[1]=a0.y; mu[2]=a0.z; mu[3]=a0.w;
      mu[4]=a1.x; mu[5]=a1.y; mu[6]=a1.z; mu[7]=a1.w;
      s2[0]=b0.x; s2[1]=b0.y; s2[2]=b0.z; s2[3]=b0.w;
      s2[4]=b1.x; s2[5]=b1.y; s2[6]=b1.z; s2[7]=b1.w;
    } else {
#pragma unroll
      for (int c = 0; c < 8; ++c) { mu[c] = 0.0f; s2[c] = 0.0f; }
    }
#pragma unroll
    for (int c = 0; c < 8; ++c) {
      const float* p = nb + (c * 9 + k) * NF;   // uniform address -> s_load
      const float l2    = p[0];
      const float d     = l2 + s2[c];
      const float inv_d = RCPF(d);
      const float coef2 = l2 * inv_d;             // == l2/d == coef^2 exactly
      const float coef  = sqrtf(coef2);
      const float el    = -0.72134752044f * inv_d; // -0.5*log2(e)/d
      const float m     = mu[c];
      const float d0 = m - p[2];
      const float d1 = m - p[3];
      const float d2 = m - p[4];
      const float d3 = m - p[5];
      const float d4 = m - p[6];
      const float u0 = EXP2F(el * d0 * d0);
      const float u1 = EXP2F(el * d1 * d1);
      const float u2 = EXP2F(el * d2 * d2);
      const float u3 = EXP2F(el * d3 * d3);
      const float u4 = EXP2F(el * d4 * d4);
      // mean: q . alpha = coef * (u . alpha)
      const float dotA =
          fmaf(u0, p[7], fmaf(u1, p[8], fmaf(u2, p[9], fmaf(u3, p[10], u4 * p[11]))));
      // quad: u^T Kinv u via diag + 2*offdiag
      const float t0 = fmaf(p[12], u0, fmaf(p[17], u1, fmaf(p[18], u2, fmaf(p[19], u3, p[20] * u4))));
      const float t1 = fmaf(p[13], u1, fmaf(p[21], u2, fmaf(p[22], u3, p[23] * u4)));
      const float t2 = fmaf(p[14], u2, fmaf(p[24], u3, p[25] * u4));
      const float t3 = fmaf(p[15], u3, p[26] * u4);
      const float t4 = p[16] * u4;
      const float quad =
          fmaf(u0, t0, fmaf(u1, t1, fmaf(u2, t2, fmaf(u3, t3, u4 * t4))));
      mean_acc = fmaf(coef, dotA, mean_acc);
      qkq_acc  = fmaf(coef2, quad, qkq_acc);
    }
  }
  const int oi = r * OC_N + o;
  out[oi] = mean_acc;
  out[OUT_HALF + oi] = fmaxf(72.0f - qkq_acc, 1e-6f);
}

extern "C" void kernel_launch(void* const* d_in, const int* in_sizes, int n_in,
                              void* d_out, int out_size, void* d_ws, size_t ws_size,
                              hipStream_t stream) {
  const float* xm = (const float*)d_in[0];   // x_mean [8,32,32,8]
  const float* xv = (const float*)d_in[1];   // x_var  [8,32,32,8]
  const float* z  = (const float*)d_in[2];   // [16,72,5]
  const float* h  = (const float*)d_in[3];   // [16,72,5]
  const float* rl = (const float*)d_in[4];   // [16,72]
  float* out = (float*)d_out;                // mean(131072) ++ var(131072)
  float* nr  = (float*)d_ws;                 // 1152 * 32 floats = 147456 B

  gp_prep_kernel<<<dim3((NEU + 255) / 256), dim3(256), 0, stream>>>(z, h, rl, nr);

  dim3 grid(RTOT / 256, OC_N);               // (32, 16)
  gp_main_kernel<<<grid, dim3(256), 0, stream>>>(xm, xv, nr, out);
}